// Round 6
// baseline (1243.989 us; speedup 1.0000x reference)
//
#include <hip/hip_runtime.h>

#define ALPHA_F 0.1f
#define DEPTH 10
#define FEATS 512
#define HID 64
#define CLS 32

__device__ __forceinline__ unsigned bf16rne(float f) {
  unsigned u = __float_as_uint(f);
  return (u + 0x7fffu + ((u >> 16) & 1u)) >> 16;   // round-to-nearest-even bf16
}
__device__ __forceinline__ float blo(unsigned q) { return __uint_as_float(q << 16); }
__device__ __forceinline__ float bhi(unsigned q) { return __uint_as_float(q & 0xffff0000u); }

// ---------------- degree count + per-edge rank (rank = old count) ----------------
__global__ __launch_bounds__(256) void k_deg(const int* __restrict__ dst, int E, int N,
                                             unsigned* __restrict__ deg,
                                             unsigned* __restrict__ rank) {
  int i = blockIdx.x * 256 + threadIdx.x;
  if (i >= E) return;
  int d = dst[i];
  unsigned r = 0;
  if ((unsigned)d < (unsigned)N) r = atomicAdd(&deg[d], 1u);
  rank[i] = r;
}

// ---------------- exclusive scan over deg -> rowst[0..N] (single block) ----------------
__global__ __launch_bounds__(1024) void k_scan(const unsigned* __restrict__ deg, int N,
                                               unsigned* __restrict__ rowst) {
  __shared__ unsigned sums[1024];
  int t = threadIdx.x;
  int chunk = (N + 1023) >> 10;
  int beg = t * chunk;
  int end = min(beg + chunk, N);
  unsigned s = 0;
  for (int i = beg; i < end; ++i) s += deg[i];
  sums[t] = s;
  __syncthreads();
  for (int off = 1; off < 1024; off <<= 1) {
    unsigned v = (t >= off) ? sums[t - off] : 0u;
    __syncthreads();
    sums[t] += v;
    __syncthreads();
  }
  unsigned pre = (t == 0) ? 0u : sums[t - 1];
  for (int i = beg; i < end; ++i) { rowst[i] = pre; pre += deg[i]; }
  if (t == 1023) rowst[N] = pre;  // last thread's pre == grand total
}

// ---------------- CSR fill, atomic-free: col[rowst[d]+rank[e]] = src[e] ----------------
__global__ __launch_bounds__(256) void k_fill(const int* __restrict__ src,
                                              const int* __restrict__ dst,
                                              const unsigned* __restrict__ rank,
                                              const unsigned* __restrict__ rowst,
                                              int E, int N,
                                              int* __restrict__ col) {
  int e = blockIdx.x * 256 + threadIdx.x;
  if (e >= E) return;
  int s = src[e];
  int d = dst[e];
  if ((unsigned)s >= (unsigned)N || (unsigned)d >= (unsigned)N) return;  // safety guard
  col[rowst[d] + rank[e]] = s;
}

// ---------------- fused MLP: h0 = relu(x@W1+b1)@W2+b2, plus scaled-state prep ----------
// 128-row tile, 256 threads. GEMM1 thread tile = 8 rows (i*16+hg) x 4 cols (4*c4..+3).
// Stride-68 LDS (rows i*16+hg land on distinct bank quads). W1 read as float4 from L2.
__global__ __launch_bounds__(256) void k_mlp(const float* __restrict__ x,
                                             const float* __restrict__ W1,
                                             const float* __restrict__ b1,
                                             const float* __restrict__ W2,
                                             const float* __restrict__ b2,
                                             const unsigned* __restrict__ deg,
                                             float* __restrict__ h0,
                                             unsigned short* __restrict__ u0,
                                             float* __restrict__ rs, int N) {
  __shared__ float XHs[128 * 68];  // 34.8 KB: Xs during GEMM1, Hs (stride 68) after
  __shared__ float W2s[64 * 32];
  __shared__ float b1s[64];
  __shared__ float b2s[32];
  int t = threadIdx.x;
  int m0 = blockIdx.x * 128;

  for (int i = t; i < 64 * 32; i += 256) W2s[i] = W2[i];
  if (t < 64) b1s[t] = b1[t];
  if (t < 32) b2s[t] = b2[t];

  int c4 = t & 15;   // cols 4*c4 .. 4*c4+3
  int hg = t >> 4;   // 0..15 -> rows i*16+hg
  float acc[8][4];
#pragma unroll
  for (int i = 0; i < 8; ++i)
#pragma unroll
    for (int m = 0; m < 4; ++m) acc[i][m] = 0.f;

  for (int k0 = 0; k0 < FEATS; k0 += 64) {
    __syncthreads();
    // stage X tile [128 rows][64 k]: 2048 float4 over 256 threads (8 each)
#pragma unroll
    for (int j = 0; j < 8; ++j) {
      int F = j * 256 + t;          // 0..2047
      int r = F >> 4, q = F & 15;   // row 0..127, float4 slot 0..15
      int row = m0 + r;
      float4 v = make_float4(0.f, 0.f, 0.f, 0.f);
      if (row < N) v = *(const float4*)(x + (size_t)row * FEATS + k0 + q * 4);
      *(float4*)(XHs + r * 68 + q * 4) = v;
    }
    __syncthreads();
    const float* W1p = W1 + (size_t)k0 * 64;
#pragma unroll
    for (int k4 = 0; k4 < 16; ++k4) {
      int k = k4 * 4;
      float4 xv[8];
#pragma unroll
      for (int i = 0; i < 8; ++i) xv[i] = *(const float4*)(XHs + (i * 16 + hg) * 68 + k);
      float4 w[4];
#pragma unroll
      for (int j = 0; j < 4; ++j) w[j] = *(const float4*)(W1p + (size_t)(k + j) * 64 + c4 * 4);
#pragma unroll
      for (int j = 0; j < 4; ++j) {
#pragma unroll
        for (int i = 0; i < 8; ++i) {
          float xx = ((const float*)&xv[i])[j];
          acc[i][0] += xx * w[j].x;
          acc[i][1] += xx * w[j].y;
          acc[i][2] += xx * w[j].z;
          acc[i][3] += xx * w[j].w;
        }
      }
    }
  }
  __syncthreads();
  // bias + relu -> Hs (stride 68, reuse XHs)
#pragma unroll
  for (int i = 0; i < 8; ++i) {
    int r = i * 16 + hg;
    float4 o;
    o.x = fmaxf(acc[i][0] + b1s[c4 * 4 + 0], 0.f);
    o.y = fmaxf(acc[i][1] + b1s[c4 * 4 + 1], 0.f);
    o.z = fmaxf(acc[i][2] + b1s[c4 * 4 + 2], 0.f);
    o.w = fmaxf(acc[i][3] + b1s[c4 * 4 + 3], 0.f);
    *(float4*)(XHs + r * 68 + c4 * 4) = o;
  }
  __syncthreads();
  // layer 2: cc = t&31 (class), g = t>>5 (0..7), rows r = i*8+g
  int cc = t & 31, g = t >> 5;
#pragma unroll
  for (int i = 0; i < 16; ++i) {
    int r = i * 8 + g;
    float s = b2s[cc];
#pragma unroll
    for (int k = 0; k < 64; ++k) s += XHs[r * 68 + k] * W2s[k * 32 + cc];
    int row = m0 + r;
    if (row < N) {
      float dv = (float)deg[row];
      float rsv = rsqrtf(fmaxf(dv, 1.0f));
      h0[(size_t)row * CLS + cc] = s;
      u0[(size_t)row * CLS + cc] = (unsigned short)bf16rne(rsv * s);
      if (cc == 0) rs[row] = rsv;
    }
  }
}

// ---------------- one APPNP step on bf16 scaled state u = bf16(rs .* h) ----------------
// non-last: u_out[d] = bf16( 0.1*rs[d]*h0[d] + 0.9*rs[d]^2 * sum_e u_in[col[e]] )
// last:     out[d]   =       0.1*h0[d]       + 0.9*rs[d]   * sum_e u_in[col[e]]  (f32)
// 4 lanes per node; u row = 4 uint4 (32 bf16, 64 B); lane owns one uint4 (8 classes).
template <bool LAST>
__global__ __launch_bounds__(256) void k_prop(const unsigned* __restrict__ u_in,
                                              const float* __restrict__ h0,
                                              const float* __restrict__ rs,
                                              const unsigned* __restrict__ rowst,
                                              const int* __restrict__ col,
                                              void* __restrict__ out, int N) {
  int t = blockIdx.x * 256 + threadIdx.x;
  int node = t >> 2;
  if (node >= N) return;
  int l = t & 3;   // lane's uint4 (classes l*8 .. l*8+7)
  unsigned beg = rowst[node];
  unsigned end = rowst[node + 1];
  const uint4* up = (const uint4*)u_in + l;
  float a[8], b[8];
#pragma unroll
  for (int j = 0; j < 8; ++j) { a[j] = 0.f; b[j] = 0.f; }
  unsigned e = beg;
  for (; e + 8 <= end; e += 8) {
    int s0 = col[e + 0], s1 = col[e + 1], s2 = col[e + 2], s3 = col[e + 3];
    int s4 = col[e + 4], s5 = col[e + 5], s6 = col[e + 6], s7 = col[e + 7];
    uint4 q0 = up[(size_t)s0 * 4];
    uint4 q1 = up[(size_t)s1 * 4];
    uint4 q2 = up[(size_t)s2 * 4];
    uint4 q3 = up[(size_t)s3 * 4];
    uint4 q4 = up[(size_t)s4 * 4];
    uint4 q5 = up[(size_t)s5 * 4];
    uint4 q6 = up[(size_t)s6 * 4];
    uint4 q7 = up[(size_t)s7 * 4];
    a[0] += blo(q0.x); a[1] += bhi(q0.x); a[2] += blo(q0.y); a[3] += bhi(q0.y);
    a[4] += blo(q0.z); a[5] += bhi(q0.z); a[6] += blo(q0.w); a[7] += bhi(q0.w);
    b[0] += blo(q1.x); b[1] += bhi(q1.x); b[2] += blo(q1.y); b[3] += bhi(q1.y);
    b[4] += blo(q1.z); b[5] += bhi(q1.z); b[6] += blo(q1.w); b[7] += bhi(q1.w);
    a[0] += blo(q2.x); a[1] += bhi(q2.x); a[2] += blo(q2.y); a[3] += bhi(q2.y);
    a[4] += blo(q2.z); a[5] += bhi(q2.z); a[6] += blo(q2.w); a[7] += bhi(q2.w);
    b[0] += blo(q3.x); b[1] += bhi(q3.x); b[2] += blo(q3.y); b[3] += bhi(q3.y);
    b[4] += blo(q3.z); b[5] += bhi(q3.z); b[6] += blo(q3.w); b[7] += bhi(q3.w);
    a[0] += blo(q4.x); a[1] += bhi(q4.x); a[2] += blo(q4.y); a[3] += bhi(q4.y);
    a[4] += blo(q4.z); a[5] += bhi(q4.z); a[6] += blo(q4.w); a[7] += bhi(q4.w);
    b[0] += blo(q5.x); b[1] += bhi(q5.x); b[2] += blo(q5.y); b[3] += bhi(q5.y);
    b[4] += blo(q5.z); b[5] += bhi(q5.z); b[6] += blo(q5.w); b[7] += bhi(q5.w);
    a[0] += blo(q6.x); a[1] += bhi(q6.x); a[2] += blo(q6.y); a[3] += bhi(q6.y);
    a[4] += blo(q6.z); a[5] += bhi(q6.z); a[6] += blo(q6.w); a[7] += bhi(q6.w);
    b[0] += blo(q7.x); b[1] += bhi(q7.x); b[2] += blo(q7.y); b[3] += bhi(q7.y);
    b[4] += blo(q7.z); b[5] += bhi(q7.z); b[6] += blo(q7.w); b[7] += bhi(q7.w);
  }
  for (; e < end; ++e) {
    int s = col[e];
    uint4 q = up[(size_t)s * 4];
    a[0] += blo(q.x); a[1] += bhi(q.x); a[2] += blo(q.y); a[3] += bhi(q.y);
    a[4] += blo(q.z); a[5] += bhi(q.z); a[6] += blo(q.w); a[7] += bhi(q.w);
  }
#pragma unroll
  for (int j = 0; j < 8; ++j) a[j] += b[j];
  float rsv = rs[node];
  const float* h0p = h0 + (size_t)node * CLS + l * 8;
  float4 h0a = *(const float4*)(h0p);
  float4 h0b = *(const float4*)(h0p + 4);
  if (LAST) {
    float ca = ALPHA_F, cb = (1.0f - ALPHA_F) * rsv;
    float* op = (float*)out + (size_t)node * CLS + l * 8;
    *(float4*)(op) = make_float4(ca * h0a.x + cb * a[0], ca * h0a.y + cb * a[1],
                                 ca * h0a.z + cb * a[2], ca * h0a.w + cb * a[3]);
    *(float4*)(op + 4) = make_float4(ca * h0b.x + cb * a[4], ca * h0b.y + cb * a[5],
                                     ca * h0b.z + cb * a[6], ca * h0b.w + cb * a[7]);
  } else {
    float ca = ALPHA_F * rsv, cb = (1.0f - ALPHA_F) * rsv * rsv;
    float o0 = ca * h0a.x + cb * a[0], o1 = ca * h0a.y + cb * a[1];
    float o2 = ca * h0a.z + cb * a[2], o3 = ca * h0a.w + cb * a[3];
    float o4 = ca * h0b.x + cb * a[4], o5 = ca * h0b.y + cb * a[5];
    float o6 = ca * h0b.z + cb * a[6], o7 = ca * h0b.w + cb * a[7];
    uint4 p;
    p.x = bf16rne(o0) | (bf16rne(o1) << 16);
    p.y = bf16rne(o2) | (bf16rne(o3) << 16);
    p.z = bf16rne(o4) | (bf16rne(o5) << 16);
    p.w = bf16rne(o6) | (bf16rne(o7) << 16);
    *((uint4*)out + (size_t)node * 4 + l) = p;
  }
}

extern "C" void kernel_launch(void* const* d_in, const int* in_sizes, int n_in,
                              void* d_out, int out_size, void* d_ws, size_t ws_size,
                              hipStream_t stream) {
  const float* x = (const float*)d_in[0];
  const int* edges = (const int*)d_in[1];   // harness stages integer inputs as int32
  const float* W1 = (const float*)d_in[2];
  const float* b1 = (const float*)d_in[3];
  const float* W2 = (const float*)d_in[4];
  const float* b2 = (const float*)d_in[5];
  int N = in_sizes[0] / FEATS;
  int E = in_sizes[1] / 2;
  const int* src = edges;
  const int* dst = edges + E;

  char* ws = (char*)d_ws;
  auto align64 = [](size_t v) { return (v + 63) & ~(size_t)63; };
  size_t o = 0;
  unsigned* deg = (unsigned*)(ws + o);   o = align64(o + (size_t)N * 4);
  unsigned* rowst = (unsigned*)(ws + o); o = align64(o + (size_t)(N + 1) * 4);
  float* rs = (float*)(ws + o);          o = align64(o + (size_t)N * 4);
  int* col = (int*)(ws + o);             o = align64(o + (size_t)E * 4);
  float* h0 = (float*)(ws + o);          o = align64(o + (size_t)N * CLS * 4);
  unsigned* uA = (unsigned*)(ws + o);    o = align64(o + (size_t)N * CLS * 2);  // bf16 state
  unsigned* uB = (unsigned*)(ws + o);    o = align64(o + (size_t)N * CLS * 2);  // bf16 state
  unsigned* rank = (unsigned*)h0;        // h0 written only after k_fill consumed rank
  // total ws use ~39.6 MB

  hipMemsetAsync(deg, 0, (size_t)N * 4, stream);
  k_deg<<<(E + 255) / 256, 256, 0, stream>>>(dst, E, N, deg, rank);
  k_scan<<<1, 1024, 0, stream>>>(deg, N, rowst);
  k_fill<<<(E + 255) / 256, 256, 0, stream>>>(src, dst, rank, rowst, E, N, col);
  k_mlp<<<(N + 127) / 128, 256, 0, stream>>>(x, W1, b1, W2, b2, deg, h0,
                                             (unsigned short*)uA, rs, N);

  float* outF = (float*)d_out;
  const unsigned* uin = uA;
  for (int it = 0; it < DEPTH - 1; ++it) {
    unsigned* uo = (it & 1) ? uA : uB;
    k_prop<false><<<((N * 4) + 255) / 256, 256, 0, stream>>>(uin, h0, rs, rowst, col, uo, N);
    uin = uo;
  }
  k_prop<true><<<((N * 4) + 255) / 256, 256, 0, stream>>>(uin, h0, rs, rowst, col, outF, N);
}